// Round 4
// baseline (349.193 us; speedup 1.0000x reference)
//
#include <hip/hip_runtime.h>
#include <hip/hip_bf16.h>
#include <stdint.h>
#include <stddef.h>

#define N_PTS 100000
#define KOFF 27

typedef __attribute__((ext_vector_type(8))) __bf16 bf16x8;
typedef __attribute__((ext_vector_type(4))) float f32x4;

__device__ inline unsigned short f2bf(float f) {
  union { float f; unsigned u; } x; x.f = f;
  unsigned r = x.u + 0x7fffu + ((x.u >> 16) & 1u);
  return (unsigned short)(r >> 16);
}

// ---------------- prep (merged): W-reorder + feats->bf16 + zero rows/stats ----------------
// Wf[k][kk][nt][lane][j] = W[k][c = kk*32 + (lane>>4)*8 + j][d = nt*16 + (lane&15)]
__global__ __launch_bounds__(256) void prep_kernel(const float* __restrict__ feats,
                                                   const float* __restrict__ W1,
                                                   const float* __restrict__ W2,
                                                   unsigned short* __restrict__ featsb,
                                                   unsigned short* __restrict__ f2b,
                                                   unsigned short* __restrict__ wf1,
                                                   unsigned short* __restrict__ wf2,
                                                   float* __restrict__ stats) {
  __shared__ float sW[4096];
  int t = threadIdx.x;
  if (blockIdx.x < 54) {
    int which = blockIdx.x & 1;
    int k = blockIdx.x >> 1;
    const float* W = (which ? W2 : W1) + (size_t)k * 4096;
    unsigned short* wf = (which ? wf2 : wf1) + (size_t)k * 4096;
#pragma unroll
    for (int i = 0; i < 4; ++i)
      ((float4*)sW)[t + 256 * i] = ((const float4*)W)[t + 256 * i];
    __syncthreads();
#pragma unroll
    for (int i = 0; i < 16; ++i) {
      int o = i * 256 + t;
      int j = o & 7, l = (o >> 3) & 63, nt = (o >> 9) & 3, kk = (o >> 11) & 1;
      int c = kk * 32 + ((l >> 4) << 3) + j;
      int d = nt * 16 + (l & 15);
      wf[o] = f2bf(sW[c * 64 + d]);
    }
    return;
  }
  int fb = blockIdx.x - 54;
  int NB = gridDim.x - 54;
  const int NF4 = N_PTS * 16;
  for (int i = fb * 256 + t; i < NF4; i += NB * 256) {
    float4 v = ((const float4*)feats)[i];
    ushort4 o;
    o.x = f2bf(v.x); o.y = f2bf(v.y); o.z = f2bf(v.z); o.w = f2bf(v.w);
    ((ushort4*)featsb)[i] = o;
  }
  if (fb == 0) {
    if (t < 256) stats[t] = 0.f;
    uint4 z = make_uint4(0u, 0u, 0u, 0u);
    if (t < 8)            ((uint4*)(featsb + (size_t)N_PTS * 64))[t] = z;
    if (t >= 8 && t < 16) ((uint4*)(f2b    + (size_t)N_PTS * 64))[t - 8] = z;
  }
}

// ---------------- conv: gathered GEMM via mfma_f32_16x16x32_bf16 + fused BN stats ----------------
#define MFMA16(a, b, c) __builtin_amdgcn_mfma_f32_16x16x32_bf16(__builtin_bit_cast(bf16x8, a), __builtin_bit_cast(bf16x8, b), c, 0, 0, 0)

// One k-step: load B(k), prefetch A(k+1) via (giN,mN), prefetch idx/mask(k+2) into (giF,mF),
// then 8 MFMAs consuming (Ac0,Ac1) and B(k).
#define STEP(Ac0, Ac1, An0, An1, giN, mN, giF, mF, kcur)                        \
  {                                                                             \
    const uint4* bp = wfv + (size_t)(kcur) * 512 + lane;                        \
    uint4 b0 = bp[0],   b1 = bp[64],  b2 = bp[128], b3 = bp[192];               \
    uint4 b4 = bp[256], b5 = bp[320], b6 = bp[384], b7 = bp[448];               \
    {                                                                           \
      int gie = (mN != 0.f) ? giN : N_PTS;                                      \
      const char* rp = (const char*)fin + (size_t)gie * 128 + g16;              \
      An0 = *(const uint4*)rp;                                                  \
      An1 = *(const uint4*)(rp + 64);                                           \
    }                                                                           \
    {                                                                           \
      int kf = ((kcur) + 2 <= 26) ? (kcur) + 2 : 26;                            \
      giF = idxp[(size_t)kf * N_PTS];                                           \
      float mt = mp[(size_t)kf * N_PTS];                                        \
      mF = valid ? mt : 0.f;                                                    \
    }                                                                           \
    a0 = MFMA16(Ac0, b0, a0);                                                   \
    a1 = MFMA16(Ac0, b1, a1);                                                   \
    a2 = MFMA16(Ac0, b2, a2);                                                   \
    a3 = MFMA16(Ac0, b3, a3);                                                   \
    a0 = MFMA16(Ac1, b4, a0);                                                   \
    a1 = MFMA16(Ac1, b5, a1);                                                   \
    a2 = MFMA16(Ac1, b6, a2);                                                   \
    a3 = MFMA16(Ac1, b7, a3);                                                   \
  }

__global__ __launch_bounds__(256, 4) void conv_kernel(
    const unsigned short* __restrict__ fin,   // [N+1,64] bf16 bits; row N_PTS = zeros
    const unsigned short* __restrict__ wf,    // fragment-ordered W, bf16 bits
    const int* __restrict__ idx,              // [K,N]
    const float* __restrict__ mask,           // [K,N] in {0,1}
    float* __restrict__ yout,                 // [N,64] f32 (pre-BN)
    float* __restrict__ gsum,                 // [64]
    float* __restrict__ gsq)                  // [64]
{
  int lane = threadIdx.x & 63;
  int wid  = threadIdx.x >> 6;
  int m    = lane & 15;       // M-row within wave tile (A) / N-col (B,C)
  int g    = lane >> 4;       // k-group 0..3
  int g16  = g * 16;
  int n0   = blockIdx.x * 64 + wid * 16;
  int n    = n0 + m;
  bool valid = n < N_PTS;
  int nc = valid ? n : (N_PTS - 1);

  const int*   idxp = idx + nc;
  const float* mp   = mask + nc;
  const uint4* wfv  = (const uint4*)wf;

  f32x4 a0, a1, a2, a3;
#pragma unroll
  for (int r = 0; r < 4; ++r) { a0[r] = 0.f; a1[r] = 0.f; a2[r] = 0.f; a3[r] = 0.f; }

  uint4 Aa0, Aa1, Ab0, Ab1;
  int gi_a, gi_b; float m_a, m_b;

  // prologue: idx(k=0) -> A(k=0) into Aa; idx(k=1) into (gi_b,m_b)
  gi_a = idxp[0];
  { float mt = mp[0]; m_a = valid ? mt : 0.f; }
  {
    int gie = (m_a != 0.f) ? gi_a : N_PTS;
    const char* rp = (const char*)fin + (size_t)gie * 128 + g16;
    Aa0 = *(const uint4*)rp;
    Aa1 = *(const uint4*)(rp + 64);
  }
  gi_b = idxp[N_PTS];
  { float mt = mp[N_PTS]; m_b = valid ? mt : 0.f; }

  for (int kk = 0; kk < 13; ++kk) {
    int k = 2 * kk;
    STEP(Aa0, Aa1, Ab0, Ab1, gi_b, m_b, gi_a, m_a, k);
    STEP(Ab0, Ab1, Aa0, Aa1, gi_a, m_a, gi_b, m_b, k + 1);
  }
  // epilogue: k = 26 with Aa
  {
    const uint4* bp = wfv + (size_t)26 * 512 + lane;
    uint4 b0 = bp[0],   b1 = bp[64],  b2 = bp[128], b3 = bp[192];
    uint4 b4 = bp[256], b5 = bp[320], b6 = bp[384], b7 = bp[448];
    a0 = MFMA16(Aa0, b0, a0);
    a1 = MFMA16(Aa0, b1, a1);
    a2 = MFMA16(Aa0, b2, a2);
    a3 = MFMA16(Aa0, b3, a3);
    a0 = MFMA16(Aa1, b4, a0);
    a1 = MFMA16(Aa1, b5, a1);
    a2 = MFMA16(Aa1, b6, a2);
    a3 = MFMA16(Aa1, b7, a3);
  }

  // C/D layout (m89): col = lane&15, row = (lane>>4)*4 + r
  __shared__ float s_sum[64], s_sq[64];
  if (threadIdx.x < 64) { s_sum[threadIdx.x] = 0.f; s_sq[threadIdx.x] = 0.f; }
  __syncthreads();

  float s0 = 0.f, q0 = 0.f, s1 = 0.f, q1 = 0.f, s2 = 0.f, q2 = 0.f, s3 = 0.f, q3 = 0.f;
#pragma unroll
  for (int r = 0; r < 4; ++r) {
    int row = n0 + g * 4 + r;
    bool rv = row < N_PTS;
    float v0 = a0[r]; s0 += v0; q0 += v0 * v0;
    float v1 = a1[r]; s1 += v1; q1 += v1 * v1;
    float v2 = a2[r]; s2 += v2; q2 += v2 * v2;
    float v3 = a3[r]; s3 += v3; q3 += v3 * v3;
    if (rv) {
      float* yr = yout + (size_t)row * 64;
      yr[m]      = v0;
      yr[16 + m] = v1;
      yr[32 + m] = v2;
      yr[48 + m] = v3;
    }
  }
  atomicAdd(&s_sum[m],      s0); atomicAdd(&s_sq[m],      q0);
  atomicAdd(&s_sum[16 + m], s1); atomicAdd(&s_sq[16 + m], q1);
  atomicAdd(&s_sum[32 + m], s2); atomicAdd(&s_sq[32 + m], q2);
  atomicAdd(&s_sum[48 + m], s3); atomicAdd(&s_sq[48 + m], q3);
  __syncthreads();
  if (threadIdx.x < 64) {
    atomicAdd(&gsum[threadIdx.x], s_sum[threadIdx.x]);
    atomicAdd(&gsq[threadIdx.x],  s_sq[threadIdx.x]);
  }
}

// ---------------- BN1 + ReLU -> bf16 ----------------
__global__ void bn1_kernel(const float* __restrict__ y,
                           const float* __restrict__ sum,
                           const float* __restrict__ sq,
                           const float* __restrict__ gamma,
                           const float* __restrict__ beta,
                           unsigned short* __restrict__ outb) {
  __shared__ float s_scale[64], s_shift[64];
  if (threadIdx.x < 64) {
    int c = threadIdx.x;
    float mean = sum[c] * (1.f / N_PTS);
    float var  = sq[c] * (1.f / N_PTS) - mean * mean;
    float inv  = rsqrtf(var + 1e-5f);
    float sc   = gamma[c] * inv;
    s_scale[c] = sc;
    s_shift[c] = beta[c] - mean * sc;
  }
  __syncthreads();
  int tid = blockIdx.x * blockDim.x + threadIdx.x;
  int stride = gridDim.x * blockDim.x;
  const int NT = N_PTS * 16;
  for (int i = tid; i < NT; i += stride) {
    float4 v = ((const float4*)y)[i];
    int c = (i * 4) & 63;
    float r0 = fmaxf(v.x * s_scale[c]     + s_shift[c],     0.f);
    float r1 = fmaxf(v.y * s_scale[c + 1] + s_shift[c + 1], 0.f);
    float r2 = fmaxf(v.z * s_scale[c + 2] + s_shift[c + 2], 0.f);
    float r3 = fmaxf(v.w * s_scale[c + 3] + s_shift[c + 3], 0.f);
    ushort4 o;
    o.x = f2bf(r0); o.y = f2bf(r1); o.z = f2bf(r2); o.w = f2bf(r3);
    ((ushort4*)outb)[i] = o;
  }
}

// ---------------- BN2 + residual + ReLU -> f32 ----------------
__global__ void bn2_kernel(const float* __restrict__ y,
                           const float* __restrict__ sum,
                           const float* __restrict__ sq,
                           const float* __restrict__ gamma,
                           const float* __restrict__ beta,
                           const float* __restrict__ feats,
                           float* __restrict__ out) {
  __shared__ float s_scale[64], s_shift[64];
  if (threadIdx.x < 64) {
    int c = threadIdx.x;
    float mean = sum[c] * (1.f / N_PTS);
    float var  = sq[c] * (1.f / N_PTS) - mean * mean;
    float inv  = rsqrtf(var + 1e-5f);
    float sc   = gamma[c] * inv;
    s_scale[c] = sc;
    s_shift[c] = beta[c] - mean * sc;
  }
  __syncthreads();
  int tid = blockIdx.x * blockDim.x + threadIdx.x;
  int stride = gridDim.x * blockDim.x;
  const int NT = N_PTS * 16;
  for (int i = tid; i < NT; i += stride) {
    float4 v = ((const float4*)y)[i];
    float4 f = ((const float4*)feats)[i];
    int c = (i * 4) & 63;
    float4 o;
    o.x = fmaxf(v.x * s_scale[c]     + s_shift[c]     + f.x, 0.f);
    o.y = fmaxf(v.y * s_scale[c + 1] + s_shift[c + 1] + f.y, 0.f);
    o.z = fmaxf(v.z * s_scale[c + 2] + s_shift[c + 2] + f.z, 0.f);
    o.w = fmaxf(v.w * s_scale[c + 3] + s_shift[c + 3] + f.w, 0.f);
    ((float4*)out)[i] = o;
  }
}

// ---------------- launch ----------------
extern "C" void kernel_launch(void* const* d_in, const int* in_sizes, int n_in,
                              void* d_out, int out_size, void* d_ws, size_t ws_size,
                              hipStream_t stream) {
  const float* feats  = (const float*)d_in[0];
  const float* W1     = (const float*)d_in[1];
  const float* gamma1 = (const float*)d_in[2];
  const float* beta1  = (const float*)d_in[3];
  const float* W2     = (const float*)d_in[4];
  const float* gamma2 = (const float*)d_in[5];
  const float* beta2  = (const float*)d_in[6];
  const int*   idx1   = (const int*)d_in[7];
  const float* mask1  = (const float*)d_in[8];
  const int*   idx2   = (const int*)d_in[9];
  const float* mask2  = (const float*)d_in[10];
  float* out = (float*)d_out;

  char* ws = (char*)d_ws;
  unsigned short* featsb = (unsigned short*)(ws + 0);          // (N+1)*128 B
  unsigned short* wf1    = (unsigned short*)(ws + 12800768);   // 221,184 B
  unsigned short* wf2    = (unsigned short*)(ws + 13021952);   // 221,184 B
  float*          stats  = (float*)(ws + 13243136);            // 1,024 B
  unsigned short* f2b    = (unsigned short*)(ws + 13244160);   // (N+1)*128 B

  float* sum1 = stats;       float* sq1 = stats + 64;
  float* sum2 = stats + 128; float* sq2 = stats + 192;

  float* y = out;  // f32 [N,64] staging; dead before each overwrite

  prep_kernel<<<54 + 640, 256, 0, stream>>>(feats, W1, W2, featsb, f2b, wf1, wf2, stats);

  const int CONV_GRID = (N_PTS + 63) / 64;  // 1563
  conv_kernel<<<CONV_GRID, 256, 0, stream>>>(featsb, wf1, idx1, mask1, y, sum1, sq1);
  bn1_kernel<<<1024, 256, 0, stream>>>(y, sum1, sq1, gamma1, beta1, f2b);
  conv_kernel<<<CONV_GRID, 256, 0, stream>>>(f2b, wf2, idx2, mask2, y, sum2, sq2);
  bn2_kernel<<<1024, 256, 0, stream>>>(y, sum2, sq2, gamma2, beta2, feats, out);
}

// Round 5
// 300.601 us; speedup vs baseline: 1.1616x; 1.1616x over previous
//
#include <hip/hip_runtime.h>
#include <hip/hip_bf16.h>
#include <stdint.h>
#include <stddef.h>

#define N_PTS 100000
#define KOFF 27

typedef __attribute__((ext_vector_type(8))) __bf16 bf16x8;
typedef __attribute__((ext_vector_type(4))) float f32x4;

__device__ inline unsigned short f2bf(float f) {
  union { float f; unsigned u; } x; x.f = f;
  unsigned r = x.u + 0x7fffu + ((x.u >> 16) & 1u);
  return (unsigned short)(r >> 16);
}

// ---------------- prep (merged): W-reorder + feats->bf16 + zero rows/stats ----------------
// Wf[k][kk][nt][lane][j] = W[k][c = kk*32 + (lane>>4)*8 + j][d = nt*16 + (lane&15)]
__global__ __launch_bounds__(256) void prep_kernel(const float* __restrict__ feats,
                                                   const float* __restrict__ W1,
                                                   const float* __restrict__ W2,
                                                   unsigned short* __restrict__ featsb,
                                                   unsigned short* __restrict__ f2b,
                                                   unsigned short* __restrict__ wf1,
                                                   unsigned short* __restrict__ wf2,
                                                   float* __restrict__ stats) {
  __shared__ float sW[4096];
  int t = threadIdx.x;
  if (blockIdx.x < 54) {
    int which = blockIdx.x & 1;
    int k = blockIdx.x >> 1;
    const float* W = (which ? W2 : W1) + (size_t)k * 4096;
    unsigned short* wf = (which ? wf2 : wf1) + (size_t)k * 4096;
#pragma unroll
    for (int i = 0; i < 4; ++i)
      ((float4*)sW)[t + 256 * i] = ((const float4*)W)[t + 256 * i];
    __syncthreads();
#pragma unroll
    for (int i = 0; i < 16; ++i) {
      int o = i * 256 + t;
      int j = o & 7, l = (o >> 3) & 63, nt = (o >> 9) & 3, kk = (o >> 11) & 1;
      int c = kk * 32 + ((l >> 4) << 3) + j;
      int d = nt * 16 + (l & 15);
      wf[o] = f2bf(sW[c * 64 + d]);
    }
    return;
  }
  int fb = blockIdx.x - 54;
  int NB = gridDim.x - 54;
  const int NF4 = N_PTS * 16;
  for (int i = fb * 256 + t; i < NF4; i += NB * 256) {
    float4 v = ((const float4*)feats)[i];
    ushort4 o;
    o.x = f2bf(v.x); o.y = f2bf(v.y); o.z = f2bf(v.z); o.w = f2bf(v.w);
    ((ushort4*)featsb)[i] = o;
  }
  if (fb == 0) {
    if (t < 256) stats[t] = 0.f;
    uint4 z = make_uint4(0u, 0u, 0u, 0u);
    if (t < 8)            ((uint4*)(featsb + (size_t)N_PTS * 64))[t] = z;
    if (t >= 8 && t < 16) ((uint4*)(f2b    + (size_t)N_PTS * 64))[t - 8] = z;
  }
}

// ---------------- conv: gathered GEMM, B shared via double-buffered LDS ----------------
#define MFMA16(a, b, c) __builtin_amdgcn_mfma_f32_16x16x32_bf16(__builtin_bit_cast(bf16x8, a), __builtin_bit_cast(bf16x8, b), c, 0, 0, 0)

// STEP k: stage B(k+1) (global->reg early, reg->LDS late), gather A(k+1), prefetch
// idx/mask(k+2), ds_read B(k) + 16 MFMAs, barrier, flip buffer.
#define STEP(kcur, Aca0, Acb0, Aca1, Acb1, Ana0, Anb0, Ana1, Anb1,              \
             iN0, mN0, iN1, mN1, iF0, mF0, iF1, mF1)                            \
  {                                                                             \
    const size_t kn = (size_t)((kcur) + 1) * 8192;                              \
    S0 = *(const uint4*)(wfB + kn + t16);                                       \
    S1 = *(const uint4*)(wfB + kn + 4096 + t16);                                \
    {                                                                           \
      int gie = (mN0 != 0.f) ? iN0 : N_PTS;                                     \
      const char* rp = (const char*)fin + (size_t)gie * 128 + g16;              \
      Ana0 = *(const uint4*)rp; Anb0 = *(const uint4*)(rp + 64);                \
    }                                                                           \
    {                                                                           \
      int gie = (mN1 != 0.f) ? iN1 : N_PTS;                                     \
      const char* rp = (const char*)fin + (size_t)gie * 128 + g16;              \
      Ana1 = *(const uint4*)rp; Anb1 = *(const uint4*)(rp + 64);                \
    }                                                                           \
    {                                                                           \
      int kf = ((kcur) + 2 <= 26) ? (kcur) + 2 : 26;                            \
      iF0 = idxp0[(size_t)kf * N_PTS];                                          \
      float mt0 = mp0[(size_t)kf * N_PTS]; mF0 = v0 ? mt0 : 0.f;                \
      iF1 = idxp1[(size_t)kf * N_PTS];                                          \
      float mt1 = mp1[(size_t)kf * N_PTS]; mF1 = v1 ? mt1 : 0.f;                \
    }                                                                           \
    {                                                                           \
      const uint4* bL = (const uint4*)sB[cur];                                  \
      uint4 b0 = bL[lane],       b1 = bL[64 + lane];                            \
      uint4 b2 = bL[128 + lane], b3 = bL[192 + lane];                           \
      uint4 b4 = bL[256 + lane], b5 = bL[320 + lane];                           \
      uint4 b6 = bL[384 + lane], b7 = bL[448 + lane];                           \
      a00 = MFMA16(Aca0, b0, a00); a01 = MFMA16(Aca0, b1, a01);                 \
      a02 = MFMA16(Aca0, b2, a02); a03 = MFMA16(Aca0, b3, a03);                 \
      a10 = MFMA16(Aca1, b0, a10); a11 = MFMA16(Aca1, b1, a11);                 \
      a12 = MFMA16(Aca1, b2, a12); a13 = MFMA16(Aca1, b3, a13);                 \
      a00 = MFMA16(Acb0, b4, a00); a01 = MFMA16(Acb0, b5, a01);                 \
      a02 = MFMA16(Acb0, b6, a02); a03 = MFMA16(Acb0, b7, a03);                 \
      a10 = MFMA16(Acb1, b4, a10); a11 = MFMA16(Acb1, b5, a11);                 \
      a12 = MFMA16(Acb1, b6, a12); a13 = MFMA16(Acb1, b7, a13);                 \
    }                                                                           \
    {                                                                           \
      uint4* wL = (uint4*)sB[cur ^ 1];                                          \
      wL[t] = S0; wL[t + 256] = S1;                                             \
    }                                                                           \
    __syncthreads();                                                            \
    cur ^= 1;                                                                   \
  }

__global__ __launch_bounds__(256, 3) void conv_kernel(
    const unsigned short* __restrict__ fin,   // [N+1,64] bf16 bits; row N_PTS = zeros
    const unsigned short* __restrict__ wf,    // fragment-ordered W, bf16 bits
    const int* __restrict__ idx,              // [K,N]
    const float* __restrict__ mask,           // [K,N] in {0,1}
    float* __restrict__ yout,                 // [N,64] f32 (pre-BN)
    float* __restrict__ gsum,                 // [64]
    float* __restrict__ gsq)                  // [64]
{
  __shared__ __align__(16) unsigned char sB[2][8192];
  __shared__ float s_sum[64], s_sq[64];

  int t    = threadIdx.x;
  int lane = t & 63;
  int wid  = t >> 6;
  int m    = lane & 15;       // row-in-group (A) / col-in-16 (C)
  int g    = lane >> 4;       // k-group 0..3
  int g16  = g * 16;
  size_t t16 = (size_t)t * 16;
  int nw   = blockIdx.x * 128 + wid * 32;   // wave's first row
  int n0r  = nw + m;
  int n1r  = nw + 16 + m;
  bool v0  = n0r < N_PTS;
  bool v1  = n1r < N_PTS;
  int nc0  = v0 ? n0r : 0;
  int nc1  = v1 ? n1r : 0;

  const int*   idxp0 = idx + nc0;
  const int*   idxp1 = idx + nc1;
  const float* mp0   = mask + nc0;
  const float* mp1   = mask + nc1;
  const char*  wfB   = (const char*)wf;

  if (t < 64) { s_sum[t] = 0.f; s_sq[t] = 0.f; }

  f32x4 a00, a01, a02, a03, a10, a11, a12, a13;
#pragma unroll
  for (int r = 0; r < 4; ++r) {
    a00[r] = 0.f; a01[r] = 0.f; a02[r] = 0.f; a03[r] = 0.f;
    a10[r] = 0.f; a11[r] = 0.f; a12[r] = 0.f; a13[r] = 0.f;
  }

  uint4 Aa0, Ab0, Aa1, Ab1;   // A set "a" (rg0: Aa0/Ab0 halves, rg1: Aa1/Ab1)
  uint4 Ba0, Bb0, Ba1, Bb1;   // A set "b"
  uint4 S0, S1;
  int iA0, iA1, iB0, iB1;
  float mA0, mA1, mB0, mB1;
  int cur = 0;

  // ---- prologue ----
  iA0 = idxp0[0]; { float mt = mp0[0]; mA0 = v0 ? mt : 0.f; }
  iA1 = idxp1[0]; { float mt = mp1[0]; mA1 = v1 ? mt : 0.f; }
  S0 = *(const uint4*)(wfB + t16);
  S1 = *(const uint4*)(wfB + 4096 + t16);
  {
    int gie = (mA0 != 0.f) ? iA0 : N_PTS;
    const char* rp = (const char*)fin + (size_t)gie * 128 + g16;
    Aa0 = *(const uint4*)rp; Ab0 = *(const uint4*)(rp + 64);
  }
  {
    int gie = (mA1 != 0.f) ? iA1 : N_PTS;
    const char* rp = (const char*)fin + (size_t)gie * 128 + g16;
    Aa1 = *(const uint4*)rp; Ab1 = *(const uint4*)(rp + 64);
  }
  iB0 = idxp0[N_PTS]; { float mt = mp0[N_PTS]; mB0 = v0 ? mt : 0.f; }
  iB1 = idxp1[N_PTS]; { float mt = mp1[N_PTS]; mB1 = v1 ? mt : 0.f; }
  {
    uint4* wL = (uint4*)sB[0];
    wL[t] = S0; wL[t + 256] = S1;
  }
  __syncthreads();

  // ---- main loop: 13 pairs cover k = 0..25 ----
  for (int kk = 0; kk < 13; ++kk) {
    int k = 2 * kk;
    STEP(k,     Aa0, Ab0, Aa1, Ab1,  Ba0, Bb0, Ba1, Bb1,
         iB0, mB0, iB1, mB1,  iA0, mA0, iA1, mA1);
    STEP(k + 1, Ba0, Bb0, Ba1, Bb1,  Aa0, Ab0, Aa1, Ab1,
         iA0, mA0, iA1, mA1,  iB0, mB0, iB1, mB1);
  }

  // ---- epilogue: k = 26, compute only ----
  {
    const uint4* bL = (const uint4*)sB[cur];
    uint4 b0 = bL[lane],       b1 = bL[64 + lane];
    uint4 b2 = bL[128 + lane], b3 = bL[192 + lane];
    uint4 b4 = bL[256 + lane], b5 = bL[320 + lane];
    uint4 b6 = bL[384 + lane], b7 = bL[448 + lane];
    a00 = MFMA16(Aa0, b0, a00); a01 = MFMA16(Aa0, b1, a01);
    a02 = MFMA16(Aa0, b2, a02); a03 = MFMA16(Aa0, b3, a03);
    a10 = MFMA16(Aa1, b0, a10); a11 = MFMA16(Aa1, b1, a11);
    a12 = MFMA16(Aa1, b2, a12); a13 = MFMA16(Aa1, b3, a13);
    a00 = MFMA16(Ab0, b4, a00); a01 = MFMA16(Ab0, b5, a01);
    a02 = MFMA16(Ab0, b6, a02); a03 = MFMA16(Ab0, b7, a03);
    a10 = MFMA16(Ab1, b4, a10); a11 = MFMA16(Ab1, b5, a11);
    a12 = MFMA16(Ab1, b6, a12); a13 = MFMA16(Ab1, b7, a13);
  }

  // ---- epilogue: write y + fused BN stats ----
  // C/D layout (m89): col = lane&15, row = (lane>>4)*4 + r
  float s0 = 0.f, q0 = 0.f, s1 = 0.f, q1 = 0.f;
  float s2 = 0.f, q2 = 0.f, s3 = 0.f, q3 = 0.f;
#pragma unroll
  for (int r = 0; r < 4; ++r) {
    int row0 = nw + g * 4 + r;
    int row1 = nw + 16 + g * 4 + r;
    float u0 = a00[r], u1 = a01[r], u2 = a02[r], u3 = a03[r];
    float w0 = a10[r], w1 = a11[r], w2 = a12[r], w3 = a13[r];
    s0 += u0 + w0; q0 += u0 * u0 + w0 * w0;
    s1 += u1 + w1; q1 += u1 * u1 + w1 * w1;
    s2 += u2 + w2; q2 += u2 * u2 + w2 * w2;
    s3 += u3 + w3; q3 += u3 * u3 + w3 * w3;
    if (row0 < N_PTS) {
      float* yr = yout + (size_t)row0 * 64;
      yr[m] = u0; yr[16 + m] = u1; yr[32 + m] = u2; yr[48 + m] = u3;
    }
    if (row1 < N_PTS) {
      float* yr = yout + (size_t)row1 * 64;
      yr[m] = w0; yr[16 + m] = w1; yr[32 + m] = w2; yr[48 + m] = w3;
    }
  }
  atomicAdd(&s_sum[m],      s0); atomicAdd(&s_sq[m],      q0);
  atomicAdd(&s_sum[16 + m], s1); atomicAdd(&s_sq[16 + m], q1);
  atomicAdd(&s_sum[32 + m], s2); atomicAdd(&s_sq[32 + m], q2);
  atomicAdd(&s_sum[48 + m], s3); atomicAdd(&s_sq[48 + m], q3);
  __syncthreads();
  if (t < 64) {
    atomicAdd(&gsum[t], s_sum[t]);
    atomicAdd(&gsq[t],  s_sq[t]);
  }
}

// ---------------- BN1 + ReLU -> bf16 ----------------
__global__ void bn1_kernel(const float* __restrict__ y,
                           const float* __restrict__ sum,
                           const float* __restrict__ sq,
                           const float* __restrict__ gamma,
                           const float* __restrict__ beta,
                           unsigned short* __restrict__ outb) {
  __shared__ float s_scale[64], s_shift[64];
  if (threadIdx.x < 64) {
    int c = threadIdx.x;
    float mean = sum[c] * (1.f / N_PTS);
    float var  = sq[c] * (1.f / N_PTS) - mean * mean;
    float inv  = rsqrtf(var + 1e-5f);
    float sc   = gamma[c] * inv;
    s_scale[c] = sc;
    s_shift[c] = beta[c] - mean * sc;
  }
  __syncthreads();
  int tid = blockIdx.x * blockDim.x + threadIdx.x;
  int stride = gridDim.x * blockDim.x;
  const int NT = N_PTS * 16;
  for (int i = tid; i < NT; i += stride) {
    float4 v = ((const float4*)y)[i];
    int c = (i * 4) & 63;
    float r0 = fmaxf(v.x * s_scale[c]     + s_shift[c],     0.f);
    float r1 = fmaxf(v.y * s_scale[c + 1] + s_shift[c + 1], 0.f);
    float r2 = fmaxf(v.z * s_scale[c + 2] + s_shift[c + 2], 0.f);
    float r3 = fmaxf(v.w * s_scale[c + 3] + s_shift[c + 3], 0.f);
    ushort4 o;
    o.x = f2bf(r0); o.y = f2bf(r1); o.z = f2bf(r2); o.w = f2bf(r3);
    ((ushort4*)outb)[i] = o;
  }
}

// ---------------- BN2 + residual + ReLU -> f32 ----------------
__global__ void bn2_kernel(const float* __restrict__ y,
                           const float* __restrict__ sum,
                           const float* __restrict__ sq,
                           const float* __restrict__ gamma,
                           const float* __restrict__ beta,
                           const float* __restrict__ feats,
                           float* __restrict__ out) {
  __shared__ float s_scale[64], s_shift[64];
  if (threadIdx.x < 64) {
    int c = threadIdx.x;
    float mean = sum[c] * (1.f / N_PTS);
    float var  = sq[c] * (1.f / N_PTS) - mean * mean;
    float inv  = rsqrtf(var + 1e-5f);
    float sc   = gamma[c] * inv;
    s_scale[c] = sc;
    s_shift[c] = beta[c] - mean * sc;
  }
  __syncthreads();
  int tid = blockIdx.x * blockDim.x + threadIdx.x;
  int stride = gridDim.x * blockDim.x;
  const int NT = N_PTS * 16;
  for (int i = tid; i < NT; i += stride) {
    float4 v = ((const float4*)y)[i];
    float4 f = ((const float4*)feats)[i];
    int c = (i * 4) & 63;
    float4 o;
    o.x = fmaxf(v.x * s_scale[c]     + s_shift[c]     + f.x, 0.f);
    o.y = fmaxf(v.y * s_scale[c + 1] + s_shift[c + 1] + f.y, 0.f);
    o.z = fmaxf(v.z * s_scale[c + 2] + s_shift[c + 2] + f.z, 0.f);
    o.w = fmaxf(v.w * s_scale[c + 3] + s_shift[c + 3] + f.w, 0.f);
    ((float4*)out)[i] = o;
  }
}

// ---------------- launch ----------------
extern "C" void kernel_launch(void* const* d_in, const int* in_sizes, int n_in,
                              void* d_out, int out_size, void* d_ws, size_t ws_size,
                              hipStream_t stream) {
  const float* feats  = (const float*)d_in[0];
  const float* W1     = (const float*)d_in[1];
  const float* gamma1 = (const float*)d_in[2];
  const float* beta1  = (const float*)d_in[3];
  const float* W2     = (const float*)d_in[4];
  const float* gamma2 = (const float*)d_in[5];
  const float* beta2  = (const float*)d_in[6];
  const int*   idx1   = (const int*)d_in[7];
  const float* mask1  = (const float*)d_in[8];
  const int*   idx2   = (const int*)d_in[9];
  const float* mask2  = (const float*)d_in[10];
  float* out = (float*)d_out;

  char* ws = (char*)d_ws;
  unsigned short* featsb = (unsigned short*)(ws + 0);          // (N+1)*128 B
  unsigned short* wf1    = (unsigned short*)(ws + 12800768);   // 221,184 B
  unsigned short* wf2    = (unsigned short*)(ws + 13021952);   // 221,184 B
  float*          stats  = (float*)(ws + 13243136);            // 1,024 B
  unsigned short* f2b    = (unsigned short*)(ws + 13244160);   // (N+1)*128 B

  float* sum1 = stats;       float* sq1 = stats + 64;
  float* sum2 = stats + 128; float* sq2 = stats + 192;

  float* y = out;  // f32 [N,64] staging; dead before each overwrite

  prep_kernel<<<54 + 640, 256, 0, stream>>>(feats, W1, W2, featsb, f2b, wf1, wf2, stats);

  const int CONV_GRID = (N_PTS + 127) / 128;  // 782
  conv_kernel<<<CONV_GRID, 256, 0, stream>>>(featsb, wf1, idx1, mask1, y, sum1, sq1);
  bn1_kernel<<<1024, 256, 0, stream>>>(y, sum1, sq1, gamma1, beta1, f2b);
  conv_kernel<<<CONV_GRID, 256, 0, stream>>>(f2b, wf2, idx2, mask2, y, sum2, sq2);
  bn2_kernel<<<1024, 256, 0, stream>>>(y, sum2, sq2, gamma2, beta2, feats, out);
}